// Round 12
// baseline (280.716 us; speedup 1.0000x reference)
//
#include <hip/hip_runtime.h>

// 2-layer fused LSTM + linear head.  B=8192, T=128, D=32, H=64, gates=256.
// R12: PRODUCER/CONSUMER WAVE SPECIALIZATION — no s_barrier in the loop.
// 512 thr / 8 waves, BT=16, grid 512 (2 blocks/CU -> each SIMD: 2P+2C waves).
//   waves 0-3 (P): layer 0 only, h-slice [16w,16w+16): 12 MFMA + 4 elem/step
//   waves 4-7 (C): layer 1 only, same h-slice:          16 MFMA + 4 elem/step
// P never waits on C (L0 doesn't read h1) except a 4-deep h0 ring guard, so
// the groups drift into a persistent phase offset: C's MFMA window overlaps
// P's elem burst on the same SIMD -> VALU + MFMA pipes run concurrently
// (R4-R11: s_barrier phase-locked all waves; 5 stagger attempts were null).
// Sync: per-wave LDS step counters (min over group; counter-SUM is wrong --
// it can't prove per-wave progress).  Producer: lgkmcnt(0) then flag store
// (DS in-order). Consumer: spin poll (b32x4 + s_sleep), then sched_barrier(0)
// + memory clobber so data ds_reads can't hoist above the spin (rule #18).
// Gate math as R4-R11: log2e folded into weights (g-gate 2x), merged-rcp,
// 5 exp2 + 2 rcp = 7 hw trans/element.

#define TT  128
#define DIN 32
#define BT  16
#define L2E 1.44269504088896340736f

typedef _Float16 h8 __attribute__((ext_vector_type(8)));
typedef __fp16   p2 __attribute__((ext_vector_type(2)));
typedef float    f4 __attribute__((ext_vector_type(4)));

#define MFMA(A, B, C) __builtin_amdgcn_mfma_f32_16x16x32_f16((A), (B), (C), 0, 0, 0)

__device__ __forceinline__ h8 cvt8s(const float* p, float s) {
    float4 a = *(const float4*)p;
    float4 b = *(const float4*)(p + 4);
    union { h8 v; p2 q[4]; } u;
    u.q[0] = __builtin_amdgcn_cvt_pkrtz(a.x * s, a.y * s);
    u.q[1] = __builtin_amdgcn_cvt_pkrtz(a.z * s, a.w * s);
    u.q[2] = __builtin_amdgcn_cvt_pkrtz(b.x * s, b.y * s);
    u.q[3] = __builtin_amdgcn_cvt_pkrtz(b.z * s, b.w * s);
    return u.v;
}

__device__ __forceinline__ h8 pack8(const float4& a, const float4& b) {
    union { h8 v; p2 q[4]; } u;
    u.q[0] = __builtin_amdgcn_cvt_pkrtz(a.x, a.y);
    u.q[1] = __builtin_amdgcn_cvt_pkrtz(a.z, a.w);
    u.q[2] = __builtin_amdgcn_cvt_pkrtz(b.x, b.y);
    u.q[3] = __builtin_amdgcn_cvt_pkrtz(b.z, b.w);
    return u.v;
}

// acc = {yi', yf', yg'(2x-scaled), yo'} (log2e pre-folded); updates c, returns h.
__device__ __forceinline__ float elem(const f4& acc, float& c) {
    float Ei = __builtin_amdgcn_exp2f(-acc[0]);
    float Ef = __builtin_amdgcn_exp2f(-acc[1]);
    float Eg = __builtin_amdgcn_exp2f(-acc[2]);
    float Eo = __builtin_amdgcn_exp2f(-acc[3]);
    float a = 1.f + Ei, b = 1.f + Eg, d = 1.f + Ef;
    float P = a * b;
    float N = c * P + (1.f - Eg) * d;
    c = N * __builtin_amdgcn_rcpf(P * d);
    float Ec = __builtin_amdgcn_exp2f(-2.f * L2E * c);
    return (1.f - Ec) * __builtin_amdgcn_rcpf((1.f + Ec) * (1.f + Eo));
}

// Spin until min(c[0..3]) >= target.  Broadcast reads; sleep between polls.
__device__ __forceinline__ void waitmin4(const volatile int* c, int target) {
    for (;;) {
        int m0 = c[0], m1 = c[1], m2 = c[2], m3 = c[3];
        int m = min(min(m0, m1), min(m2, m3));
        if (m >= target) break;
        __builtin_amdgcn_s_sleep(1);
    }
    __builtin_amdgcn_sched_barrier(0);
    asm volatile("" ::: "memory");   // data reads below must reload from LDS
}

__global__ __launch_bounds__(512, 4)
void lstm2_fused(const float* __restrict__ x,
                 const float* __restrict__ wih0, const float* __restrict__ whh0,
                 const float* __restrict__ bih0, const float* __restrict__ bhh0,
                 const float* __restrict__ wih1, const float* __restrict__ whh1,
                 const float* __restrict__ bih1, const float* __restrict__ bhh1,
                 const float* __restrict__ fcw,  const float* __restrict__ fcb,
                 float* __restrict__ out)
{
    const int tid  = threadIdx.x;
    const int lane = tid & 63;
    const int wv   = tid >> 6;      // 0..7: 0-3 producer (L0), 4-7 consumer (L1)
    const int bl   = lane & 15;
    const int kg   = lane >> 4;

    // slots 0-3: h0 ring (depth 4); slots 4-5: h1 parity.  2048 B each.
    __shared__ alignas(16) unsigned short hb[6][BT * 64];   // 12 KB
    __shared__ alignas(16) int ctrP[4];
    __shared__ alignas(16) int ctrC[4];
    __shared__ float wpart[4][BT];

    for (int i = tid; i < (int)(sizeof(hb) / 4); i += 512) ((int*)hb)[i] = 0;
    if (tid < 4) { ctrP[tid] = 0; ctrC[tid] = 0; }

    const int bbase = blockIdx.x * BT;
    const int swz = (bl & 7) << 4;
    char* lb = (char*)hb;
    const int rowoff = bl * 128;
    const int rd0 = rowoff + ((16 * kg) ^ swz);
    const int rd1 = rowoff + ((64 + 16 * kg) ^ swz);

    volatile int* vP = ctrP;
    volatile int* vC = ctrC;

    __syncthreads();   // zeroed LDS + counters visible; ONLY barrier before tail

    if (wv < 4) {
        // ================= PRODUCER: layer 0 =================
        const int w = wv;
        h8 W0[4][3]; f4 b0v[4]; int wro[4];
        #pragma unroll
        for (int t = 0; t < 4; ++t) {
            const int hbse = 16 * w + 4 * t;
            const int gam  = bl & 3;
            const int g    = 64 * gam + hbse + (bl >> 2);
            const float sc = (gam == 2) ? 2.f * L2E : L2E;
            W0[t][0] = cvt8s(wih0 + g * 32 + 8 * kg, sc);
            W0[t][1] = cvt8s(whh0 + g * 64 + 8 * kg, sc);
            W0[t][2] = cvt8s(whh0 + g * 64 + 32 + 8 * kg, sc);
            #pragma unroll
            for (int r = 0; r < 4; ++r) {
                const int gr = 64 * r + hbse + kg;
                const float scr = (r == 2) ? 2.f * L2E : L2E;
                b0v[t][r] = (bih0[gr] + bhh0[gr]) * scr;
            }
            wro[t] = rowoff + ((32 * w + 8 * t + 2 * kg) ^ swz);  // h = hbse+kg
        }

        const float* xp = x + (size_t)(bbase + bl) * (TT * DIN) + 8 * kg;
        h8 xcur = pack8(*(const float4*)xp, *(const float4*)(xp + 4));
        float c0[4] = {0.f, 0.f, 0.f, 0.f};

        for (int t = 0; t < TT; ++t) {
            if (t)      waitmin4(vP, t);       // group's h0[t-1] ready
            if (t >= 4) waitmin4(vC, t - 3);   // ring slot t&3 consumed (C done t-4)

            const char* src = lb + (((t - 1) & 3) * 2048);   // t=0 -> slot 3 (zeros)
            h8 hr0 = *(const h8*)(src + rd0);
            h8 hr1 = *(const h8*)(src + rd1);
            const int tn = (t + 1 < TT) ? t + 1 : t;
            float4 xnA = *(const float4*)(xp + tn * DIN);
            float4 xnB = *(const float4*)(xp + tn * DIN + 4);

            __builtin_amdgcn_s_setprio(1);
            f4 acc[4];
            #pragma unroll
            for (int k = 0; k < 4; ++k) {
                acc[k] = b0v[k];
                acc[k] = MFMA(W0[k][1], hr0, acc[k]);
                acc[k] = MFMA(W0[k][2], hr1, acc[k]);
                acc[k] = MFMA(W0[k][0], xcur, acc[k]);
            }
            __builtin_amdgcn_s_setprio(0);

            char* dst = lb + ((t & 3) * 2048);
            #pragma unroll
            for (int k = 0; k < 4; ++k) {
                float h = elem(acc[k], c0[k]);
                *(_Float16*)(dst + wro[k]) = (_Float16)h;
            }

            asm volatile("s_waitcnt lgkmcnt(0)" ::: "memory");  // drain h0 writes
            if (lane == 0) vP[w] = t + 1;                       // publish step
            xcur = pack8(xnA, xnB);
        }
    } else {
        // ================= CONSUMER: layer 1 =================
        const int w = wv - 4;
        h8 W1[4][4]; f4 b1v[4]; int wro[4];
        #pragma unroll
        for (int t = 0; t < 4; ++t) {
            const int hbse = 16 * w + 4 * t;
            const int gam  = bl & 3;
            const int g    = 64 * gam + hbse + (bl >> 2);
            const float sc = (gam == 2) ? 2.f * L2E : L2E;
            W1[t][0] = cvt8s(wih1 + g * 64 + 8 * kg, sc);
            W1[t][1] = cvt8s(wih1 + g * 64 + 32 + 8 * kg, sc);
            W1[t][2] = cvt8s(whh1 + g * 64 + 8 * kg, sc);
            W1[t][3] = cvt8s(whh1 + g * 64 + 32 + 8 * kg, sc);
            #pragma unroll
            for (int r = 0; r < 4; ++r) {
                const int gr = 64 * r + hbse + kg;
                const float scr = (r == 2) ? 2.f * L2E : L2E;
                b1v[t][r] = (bih1[gr] + bhh1[gr]) * scr;
            }
            wro[t] = rowoff + ((32 * w + 8 * t + 2 * kg) ^ swz);
        }

        float c1[4] = {0.f, 0.f, 0.f, 0.f};
        float h1f[4] = {0.f, 0.f, 0.f, 0.f};

        for (int t = 0; t < TT; ++t) {
            waitmin4(vP, t + 1);               // h0[t] published
            if (t) waitmin4(vC, t);            // group's h1[t-1] ready

            const char* s0 = lb + ((t & 3) * 2048);                  // h0[t]
            const char* s1 = lb + 8192 + (((t - 1) & 1) * 2048);     // h1[t-1]
            h8 g0a = *(const h8*)(s0 + rd0);
            h8 g0b = *(const h8*)(s0 + rd1);
            h8 g1a = *(const h8*)(s1 + rd0);
            h8 g1b = *(const h8*)(s1 + rd1);

            __builtin_amdgcn_s_setprio(1);
            f4 acc[4];
            #pragma unroll
            for (int k = 0; k < 4; ++k) {
                acc[k] = b1v[k];
                acc[k] = MFMA(W1[k][0], g0a, acc[k]);
                acc[k] = MFMA(W1[k][1], g0b, acc[k]);
                acc[k] = MFMA(W1[k][2], g1a, acc[k]);
                acc[k] = MFMA(W1[k][3], g1b, acc[k]);
            }
            __builtin_amdgcn_s_setprio(0);

            char* dst = lb + 8192 + ((t & 1) * 2048);
            #pragma unroll
            for (int k = 0; k < 4; ++k) {
                float h = elem(acc[k], c1[k]);
                h1f[k] = h;
                if (t < TT - 1) *(_Float16*)(dst + wro[k]) = (_Float16)h;
            }

            if (t < TT - 1) {
                asm volatile("s_waitcnt lgkmcnt(0)" ::: "memory");
                if (lane == 0) vC[w] = t + 1;
            }
        }

        // head partial: out[b] += sum_h h1[b][h] * fcw[h] over this wave's 16 h
        float part = 0.f;
        #pragma unroll
        for (int k = 0; k < 4; ++k) part += h1f[k] * fcw[16 * w + 4 * k + kg];
        part += __shfl_xor(part, 16, 64);
        part += __shfl_xor(part, 32, 64);
        if (lane < 16) wpart[w][lane] = part;
    }

    __syncthreads();
    if (tid < BT)
        out[bbase + tid] = wpart[0][tid] + wpart[1][tid] + wpart[2][tid] + wpart[3][tid] + fcb[0];
}

extern "C" void kernel_launch(void* const* d_in, const int* in_sizes, int n_in,
                              void* d_out, int out_size, void* d_ws, size_t ws_size,
                              hipStream_t stream) {
    (void)in_sizes; (void)n_in; (void)d_ws; (void)ws_size; (void)out_size;
    lstm2_fused<<<dim3(8192 / BT), dim3(512), 0, stream>>>(
        (const float*)d_in[0],
        (const float*)d_in[1], (const float*)d_in[2],
        (const float*)d_in[3], (const float*)d_in[4],
        (const float*)d_in[5], (const float*)d_in[6],
        (const float*)d_in[7], (const float*)d_in[8],
        (const float*)d_in[9], (const float*)d_in[10],
        (float*)d_out);
}